// Round 13
// baseline (713.106 us; speedup 1.0000x reference)
//
#include <hip/hip_runtime.h>
#include <hip/hip_fp16.h>
#include <math.h>

#define D 64
#define WAVE 64

typedef _Float16 f16;
typedef f16 f16x8 __attribute__((ext_vector_type(8)));
typedef float f32x4 __attribute__((ext_vector_type(4)));

// ---------- helpers ----------
__device__ __forceinline__ float fast_tanh(float x) {
    // tanh(x) = 1 - 2/(exp(2x)+1); saturates correctly at +-1 (inf-safe)
    float e = __expf(2.0f * x);
    return 1.0f - 2.0f / (e + 1.0f);
}

// ---------- 0. WT[r][o][k] = fp16(W[r][k][o]) ----------
__global__ void wt_kernel(const float* __restrict__ W, f16* __restrict__ WT,
                          int n_rel) {
    int idx = blockIdx.x * blockDim.x + threadIdx.x;
    if (idx >= n_rel * D * D) return;
    int r = idx >> 12;          // /4096
    int rem = idx & 4095;
    int o = rem >> 6;
    int k = rem & 63;
    WT[idx] = (f16)W[((size_t)r << 12) + (k << 6) + o];
}

// ---------- 1. proj[n][r][o] via MFMA (fp16 in, fp32 acc, fp16 out) ----------
// (R7 A/B: MFMA proj ~117us, confirmed win.) Also spills fp16 nfeat to nf16[].
__global__ __launch_bounds__(256) void proj_kernel(
    const float* __restrict__ nfeat, const f16* __restrict__ WT,
    f16* __restrict__ proj, f16* __restrict__ nf16, int n_nodes, int n_rel) {
    __shared__ f16 Al[64 * D];   // 8KB A-tile, row-major [row][k]
    const int tid = threadIdx.x;
    const int lane = tid & 63;
    const int wid = tid >> 6;
    const int n0 = blockIdx.x * 64;

    // stage A: 1024 float4 / 256 threads = 4 iters, fp32->fp16 (+ global spill)
    {
        const float4* g4 = (const float4*)(nfeat + (size_t)n0 * D);
        int avail_rows = n_nodes - n0;
        if (avail_rows > 64) avail_rows = 64;
        const int avail4 = avail_rows * (D / 4);
#pragma unroll
        for (int i = tid; i < 64 * (D / 4); i += 256) {
            float4 v = (i < avail4) ? g4[i] : make_float4(0.f, 0.f, 0.f, 0.f);
            f16 h0 = (f16)v.x, h1 = (f16)v.y, h2 = (f16)v.z, h3 = (f16)v.w;
            f16* dp = &Al[i * 4];
            dp[0] = h0; dp[1] = h1; dp[2] = h2; dp[3] = h3;
            if (i < avail4) {
                f16* np = nf16 + (size_t)n0 * D + i * 4;
                np[0] = h0; np[1] = h1; np[2] = h2; np[3] = h3;
            }
        }
    }
    __syncthreads();

    const int g = lane >> 4;   // k-group 0..3
    const int c = lane & 15;   // col within 16-tile
    const int arow = wid * 16 + c;
    f16x8 a0 = *(const f16x8*)&Al[arow * D + g * 8];
    f16x8 a1 = *(const f16x8*)&Al[arow * D + 32 + g * 8];

    const int row_base = n0 + wid * 16 + g * 4;

    for (int r = 0; r < n_rel; ++r) {
        const f16* Wb = WT + ((size_t)r << 12);
        f32x4 acc[4] = {{0.f,0.f,0.f,0.f},{0.f,0.f,0.f,0.f},
                        {0.f,0.f,0.f,0.f},{0.f,0.f,0.f,0.f}};
#pragma unroll
        for (int t = 0; t < 4; ++t) {
            const f16* bp = Wb + (size_t)(t * 16 + c) * D + g * 8;
            f16x8 b0 = *(const f16x8*)bp;
            f16x8 b1 = *(const f16x8*)(bp + 32);
            acc[t] = __builtin_amdgcn_mfma_f32_16x16x32_f16(a0, b0, acc[t], 0, 0, 0);
            acc[t] = __builtin_amdgcn_mfma_f32_16x16x32_f16(a1, b1, acc[t], 0, 0, 0);
        }
#pragma unroll
        for (int t = 0; t < 4; ++t) {
#pragma unroll
            for (int j = 0; j < 4; ++j) {
                int n = row_base + j;
                if (n < n_nodes)
                    proj[((size_t)n * n_rel + r) * D + t * 16 + c] = (f16)acc[t][j];
            }
        }
    }
}

// ---------- 2. CSR row_ptr from sorted dst ----------
__global__ void rowptr_kernel(const int* __restrict__ dst, int* __restrict__ row_ptr,
                              int n_edges, int n_nodes) {
    int tid = blockIdx.x * blockDim.x + threadIdx.x;
    int stride = gridDim.x * blockDim.x;
    for (int e = tid; e < n_edges; e += stride) {
        int d = dst[e];
        int dprev = (e == 0) ? -1 : dst[e - 1];
        for (int v = dprev + 1; v <= d; ++v) row_ptr[v] = e;
    }
    if (tid == 0) {
        int dlast = dst[n_edges - 1];
        for (int v = dlast + 1; v <= n_nodes; ++v) row_ptr[v] = n_edges;
    }
}

// ---------- 3. FUSED att + edge-softmax + aggregation (online softmax) ----------
// R10 post-mortem: separate att+agg ~560us combined and invisible below the
// top-5 cutoff. Fuse per dst-segment: wave per node, lane = channel.
//   - h_r = proj[dst,et]: <=10 distinct rows per node -> L1-hot (kills the
//     per-edge 128B random h_r gather, ~160MB).
//   - att[] round-trip eliminated; edges visited ONCE.
//   - 4 edges per chunk: stage-major interleaved butterfly reduces (4 indep
//     shfl chains) + one flash-style rescale per chunk.
// Edge scalars (src/etype) are wave-uniform -> s_loads.
__global__ __launch_bounds__(256) void attagg_kernel(
    const f16* __restrict__ proj, const float* __restrict__ efeat,
    const int* __restrict__ src, const int* __restrict__ etype,
    const int* __restrict__ row_ptr, const f16* __restrict__ nf16,
    float* __restrict__ h_nb, int n_nodes, int n_rel) {
    const int lane = threadIdx.x & 63;
    const int wid = __builtin_amdgcn_readfirstlane(threadIdx.x >> 6);
    const int n = blockIdx.x * 4 + wid;
    if (n >= n_nodes) return;
    const int s = row_ptr[n];
    const int t = row_ptr[n + 1];

    float m = -INFINITY;   // running max
    float l = 0.0f;        // running exp-sum
    float acc = 0.0f;      // running weighted feature (this lane's channel)
    const size_t hbase = (size_t)n * n_rel;

    for (int base = s; base < t; base += 4) {
        const int tm1 = t - 1;
        const int e0 = base;
        const int e1 = (base + 1 < t) ? base + 1 : tm1;
        const int e2 = (base + 2 < t) ? base + 2 : tm1;
        const int e3 = (base + 3 < t) ? base + 3 : tm1;
        const bool p1 = base + 1 < t, p2 = base + 2 < t, p3 = base + 3 < t;

        // wave-uniform edge scalars -> s_loads
        const int s0 = src[e0], s1 = src[e1], s2 = src[e2], s3 = src[e3];
        const int q0 = etype[e0], q1 = etype[e1], q2 = etype[e2], q3 = etype[e3];

        // issue all vector loads up front (gathers + stream)
        float tr0 = (float)proj[((size_t)s0 * n_rel + q0) * D + lane];
        float tr1 = (float)proj[((size_t)s1 * n_rel + q1) * D + lane];
        float tr2 = (float)proj[((size_t)s2 * n_rel + q2) * D + lane];
        float tr3 = (float)proj[((size_t)s3 * n_rel + q3) * D + lane];
        float nf0 = (float)nf16[(size_t)s0 * D + lane];
        float nf1 = (float)nf16[(size_t)s1 * D + lane];
        float nf2 = (float)nf16[(size_t)s2 * D + lane];
        float nf3 = (float)nf16[(size_t)s3 * D + lane];
        float ef0 = efeat[(size_t)e0 * D + lane];
        float ef1 = efeat[(size_t)e1 * D + lane];
        float ef2 = efeat[(size_t)e2 * D + lane];
        float ef3 = efeat[(size_t)e3 * D + lane];
        float hr0 = (float)proj[(hbase + q0) * D + lane];  // L1-hot
        float hr1 = (float)proj[(hbase + q1) * D + lane];
        float hr2 = (float)proj[(hbase + q2) * D + lane];
        float hr3 = (float)proj[(hbase + q3) * D + lane];

        float v0 = tr0 * fast_tanh(hr0 + ef0);
        float v1 = tr1 * fast_tanh(hr1 + ef1);
        float v2 = tr2 * fast_tanh(hr2 + ef2);
        float v3 = tr3 * fast_tanh(hr3 + ef3);

        // 4 independent butterfly reductions, stage-major interleave
#pragma unroll
        for (int st = 32; st >= 1; st >>= 1) {
            v0 += __shfl_xor(v0, st);
            v1 += __shfl_xor(v1, st);
            v2 += __shfl_xor(v2, st);
            v3 += __shfl_xor(v3, st);
        }
        float a0 = v0;
        float a1 = p1 ? v1 : -INFINITY;
        float a2 = p2 ? v2 : -INFINITY;
        float a3 = p3 ? v3 : -INFINITY;

        // online softmax: one rescale per chunk
        float cm = fmaxf(fmaxf(a0, a1), fmaxf(a2, a3));
        float mn = fmaxf(m, cm);
        float sc = __expf(m - mn);   // m=-inf first chunk -> 0
        acc *= sc;
        l *= sc;
        float w0 = __expf(a0 - mn);  // padded: exp(-inf)=0
        float w1 = __expf(a1 - mn);
        float w2 = __expf(a2 - mn);
        float w3 = __expf(a3 - mn);
        l += (w0 + w1) + (w2 + w3);
        acc = fmaf(w0, nf0, acc);
        acc = fmaf(w1, nf1, acc);
        acc = fmaf(w2, nf2, acc);
        acc = fmaf(w3, nf3, acc);
        m = mn;
    }
    h_nb[(size_t)n * D + lane] = (l > 0.0f) ? acc / l : 0.0f;
}

// ---------- 4. out = lrelu((x+h)W1^T) + lrelu((x*h)W2^T) ----------
// h_nb ALIASES out: each wave reads row n fully before writing row n -> safe.
__global__ __launch_bounds__(256) void out_kernel(
    const float* __restrict__ nfeat, const float* h_nb,
    const float* __restrict__ W1, const float* __restrict__ W2,
    float* out, int n_nodes) {
    const int lane = threadIdx.x & 63;
    const int wid = __builtin_amdgcn_readfirstlane(threadIdx.x >> 6);
    float w1[D], w2[D];
#pragma unroll
    for (int i = 0; i < D; ++i) w1[i] = W1[lane * D + i];
#pragma unroll
    for (int i = 0; i < D; ++i) w2[i] = W2[lane * D + i];
    const int nwaves = gridDim.x * 4;
    for (int n = blockIdx.x * 4 + wid; n < n_nodes; n += nwaves) {
        const int nn = __builtin_amdgcn_readfirstlane(n);
        const float* x = nfeat + (size_t)nn * D;  // uniform -> s_load
        const float* h = h_nb + (size_t)nn * D;
        float a0 = 0.0f, a1 = 0.0f, b0 = 0.0f, b1 = 0.0f;
#pragma unroll
        for (int i = 0; i < D; i += 2) {
            float x0 = x[i], h0 = h[i];
            float x1 = x[i + 1], h1 = h[i + 1];
            a0 = fmaf(x0 + h0, w1[i], a0);
            b0 = fmaf(x0 * h0, w2[i], b0);
            a1 = fmaf(x1 + h1, w1[i + 1], a1);
            b1 = fmaf(x1 * h1, w2[i + 1], b1);
        }
        float a = a0 + a1, b = b0 + b1;
        a = (a > 0.0f) ? a : 0.01f * a;
        b = (b > 0.0f) ? b : 0.01f * b;
        out[(size_t)nn * D + lane] = a + b;
    }
}

// ---------- launcher ----------
extern "C" void kernel_launch(void* const* d_in, const int* in_sizes, int n_in,
                              void* d_out, int out_size, void* d_ws, size_t ws_size,
                              hipStream_t stream) {
    const float* nfeat = (const float*)d_in[0];
    const float* efeat = (const float*)d_in[1];
    const float* relw  = (const float*)d_in[2];
    const float* w1    = (const float*)d_in[3];
    const float* w2    = (const float*)d_in[4];
    const int*   src   = (const int*)d_in[5];
    const int*   dst   = (const int*)d_in[6];
    const int*   etype = (const int*)d_in[7];
    float* out = (float*)d_out;

    const int n_nodes = in_sizes[0] / D;
    const int n_edges = in_sizes[5];
    const int n_rel   = in_sizes[2] / (D * D);

    const size_t ALIGN = 256;
    const size_t proj_bytes = ((size_t)n_nodes * n_rel * D * sizeof(f16) + ALIGN - 1) & ~(ALIGN - 1);
    const size_t rp_bytes   = ((size_t)(n_nodes + 1) * sizeof(int) + ALIGN - 1) & ~(ALIGN - 1);
    const size_t wt_bytes   = ((size_t)n_rel * D * D * sizeof(f16) + ALIGN - 1) & ~(ALIGN - 1);

    // h_nb lives in d_out (out_kernel reads row n before writing row n).
    float* h_nb = out;

    char* ws = (char*)d_ws;
    f16*  proj    = (f16*)ws;
    int* row_ptr  = (int*)(ws + proj_bytes);
    f16*  wt      = (f16*)(ws + proj_bytes + rp_bytes);
    f16*  nf16    = (f16*)(ws + proj_bytes + rp_bytes + wt_bytes);

    rowptr_kernel<<<1024, 256, 0, stream>>>(dst, row_ptr, n_edges, n_nodes);

    wt_kernel<<<(n_rel * D * D + 255) / 256, 256, 0, stream>>>(relw, wt, n_rel);

    proj_kernel<<<(n_nodes + 63) / 64, 256, 0, stream>>>(nfeat, wt, proj, nf16,
                                                         n_nodes, n_rel);

    attagg_kernel<<<(n_nodes + 3) / 4, 256, 0, stream>>>(proj, efeat, src, etype,
                                                         row_ptr, nf16, h_nb,
                                                         n_nodes, n_rel);

    out_kernel<<<3200, 256, 0, stream>>>(nfeat, h_nb, w1, w2, out, n_nodes);
}